// Round 1
// 289.875 us; speedup vs baseline: 1.0187x; 1.0187x over previous
//
#include <hip/hip_runtime.h>

#define HW 128
#define KTAPS 255
#define DIMC 256

typedef short short8 __attribute__((ext_vector_type(8)));
typedef float f32x16 __attribute__((ext_vector_type(16)));

__device__ __forceinline__ short f2bf(float f) {
    return __builtin_bit_cast(short, (__bf16)f);
}
// Padded chunk addressing: 16B chunk index -> 16B slot (breaks 128B-stride bank collisions)
__device__ __forceinline__ int pad16(int c) { return c + (c >> 3); }

// Fragment layouts (v_mfma_f32_32x32x16_bf16):
//  A (MxK): elem(m,k): chunk=((m>>5)*8+(k>>4))*64 + (m&31)+32*((k>>3)&1), j=k&7
//  B (KxN): elem(k,n): chunk=((n>>5)*8+(k>>4))*64 + (n&31)+32*((k>>3)&1), j=k&7
//  C/D: col=lane&31, row=(reg&3)+8*(reg>>2)+4*(lane>>5)
//
// v2: 512 threads (8 waves) per block, same 72KB LDS -> 2 blocks/CU = 16 waves/CU
//     (4 waves/SIMD, 2x the old occupancy). Wave (wm,wn): wm=wv>>1 m-tile,
//     wn=wv&1 column half (2 of 4 n-tiles). Bw taps preloaded to regs in phase A.

__global__ __launch_bounds__(512, 4)
void sep_conv255_mfma(const float* __restrict__ x,
                      const float* __restrict__ wh,
                      const float* __restrict__ bh,
                      const float* __restrict__ ww,
                      const float* __restrict__ bw,
                      float* __restrict__ out) {
    __shared__ __align__(16) short P1[2304 * 8];  // X-frags, then Y-frags (36 KB)
    __shared__ __align__(16) short P2[2304 * 8];  // Ah-frags, then Bw-frags (36 KB)

    const int blk  = blockIdx.x;        // n*DIMC + c
    const int c    = blk & (DIMC - 1);
    const int tid  = threadIdx.x;       // 0..511
    const int lane = tid & 63;
    const int wv   = tid >> 6;          // wave id 0..7
    const int wm   = wv >> 1;           // m-tile row 0..3  (rows 32*wm..32*wm+31)
    const int wn   = wv & 1;            // column half 0..1 (n-tiles 2*wn, 2*wn+1)

    const float* __restrict__ xc  = x + (size_t)blk * (HW * HW);
    float* __restrict__ zc        = out + (size_t)blk * (HW * HW);
    const float* __restrict__ whc = wh + c * KTAPS;
    const float* __restrict__ wwc = ww + c * KTAPS;

    // ---------- Phase A: Ah frags -> P2, X bf16 frags -> P1, Bw frags -> regs ----------
#pragma unroll
    for (int i = 0; i < 4; ++i) {
        const int ch = tid + (i << 9);          // chunk 0..2047
        const int lc = ch & 63;
        const int ks = (ch >> 6) & 7;
        const int tm = ch >> 9;
        const int m  = (tm << 5) + (lc & 31);
        const int kb = (ks << 4) + ((lc >> 5) << 3);
        const float* wp = whc + (127 + kb - m); // always in [0,247]
        short8 v;
#pragma unroll
        for (int j = 0; j < 8; ++j) v[j] = f2bf(wp[j]);
        *reinterpret_cast<short8*>(&P2[pad16(ch) * 8]) = v;
    }
    {
        // thread owns column n = tid&127; gathers 8 rows -> one packed b128 write
        const int n  = tid & 127;
        const int bc = (n >> 5) << 3;
#pragma unroll
        for (int i = 0; i < 4; ++i) {
            const int rg = (tid >> 7) + (i << 2);   // 0..15
            const int r0 = rg << 3;
            float xv[8];
#pragma unroll
            for (int j = 0; j < 8; ++j) xv[j] = xc[(r0 + j) * HW + n];
            short8 v;
#pragma unroll
            for (int j = 0; j < 8; ++j) v[j] = f2bf(xv[j]);
            const int ch = (bc + (r0 >> 4)) * 64 + (n & 31) + (((r0 >> 3) & 1) << 5);
            *reinterpret_cast<short8*>(&P1[pad16(ch) * 8]) = v;
        }
    }
    // Bw taps -> registers; global-load latency hides under phase A + mm1
    short8 wreg[4];
#pragma unroll
    for (int i = 0; i < 4; ++i) {
        const int ch = tid + (i << 9);
        const int lc = ch & 63;
        const int ks = (ch >> 6) & 7;
        const int tn = ch >> 9;
        const int nn = (tn << 5) + (lc & 31);
        const int kb = (ks << 4) + ((lc >> 5) << 3);
        const float* wp = wwc + (127 + kb - nn);
#pragma unroll
        for (int j = 0; j < 8; ++j) wreg[i][j] = f2bf(wp[j]);
    }
    __syncthreads();

    // ---------- mm1: Y = Ah * X (each wave: 1 m-tile x 2 n-tiles) ----------
    f32x16 acc[2];
#pragma unroll
    for (int t = 0; t < 2; ++t)
#pragma unroll
        for (int j = 0; j < 16; ++j) acc[t][j] = 0.0f;

#pragma unroll
    for (int ks = 0; ks < 8; ++ks) {
        const short8 a = *reinterpret_cast<const short8*>(
            &P2[pad16(((wm << 3) + ks) * 64 + lane) * 8]);
#pragma unroll
        for (int tt = 0; tt < 2; ++tt) {
            const int t = (wn << 1) + tt;
            const short8 b = *reinterpret_cast<const short8*>(
                &P1[pad16(((t << 3) + ks) * 64 + lane) * 8]);
            acc[tt] = __builtin_amdgcn_mfma_f32_32x32x16_bf16(a, b, acc[tt], 0, 0, 0);
        }
    }
    __syncthreads();

    // ---------- Y(+bh) frags -> P1 ; Bw regs -> P2 ----------
    const float bhv = bh[c];
    const int hbase = (wm << 5) + ((lane >> 5) << 2);
    {
        const int s31 = lane & 31;
#pragma unroll
        for (int tt = 0; tt < 2; ++tt) {
            const int t  = (wn << 1) + tt;
            const int s  = (t << 5) + s31;
            const int cb = ((wm << 3) + (s >> 4)) * 64 + (((s >> 3) & 1) << 5);
            const int jj = s & 7;
#pragma unroll
            for (int r = 0; r < 16; ++r) {
                const int h = hbase + (r & 3) + ((r >> 2) << 3);
                P1[pad16(cb + (h & 31)) * 8 + jj] = f2bf(acc[tt][r] + bhv);
            }
        }
    }
#pragma unroll
    for (int i = 0; i < 4; ++i) {
        const int ch = tid + (i << 9);
        *reinterpret_cast<short8*>(&P2[pad16(ch) * 8]) = wreg[i];
    }
    __syncthreads();

    // ---------- mm2: Z = Y * Bw ----------
#pragma unroll
    for (int t = 0; t < 2; ++t)
#pragma unroll
        for (int j = 0; j < 16; ++j) acc[t][j] = 0.0f;

#pragma unroll
    for (int ks = 0; ks < 8; ++ks) {
        const short8 a = *reinterpret_cast<const short8*>(
            &P1[pad16(((wm << 3) + ks) * 64 + lane) * 8]);
#pragma unroll
        for (int tt = 0; tt < 2; ++tt) {
            const int t = (wn << 1) + tt;
            const short8 b = *reinterpret_cast<const short8*>(
                &P2[pad16(((t << 3) + ks) * 64 + lane) * 8]);
            acc[tt] = __builtin_amdgcn_mfma_f32_32x32x16_bf16(a, b, acc[tt], 0, 0, 0);
        }
    }

    // ---------- epilogue: Z + bw -> global ----------
    const float bwv = bw[c];
    {
        const int w31 = lane & 31;
#pragma unroll
        for (int tt = 0; tt < 2; ++tt) {
            const int w2 = (((wn << 1) + tt) << 5) + w31;
#pragma unroll
            for (int r = 0; r < 16; ++r) {
                const int h = hbase + (r & 3) + ((r >> 2) << 3);
                zc[h * HW + w2] = acc[tt][r] + bwv;
            }
        }
    }
}

extern "C" void kernel_launch(void* const* d_in, const int* in_sizes, int n_in,
                              void* d_out, int out_size, void* d_ws, size_t ws_size,
                              hipStream_t stream) {
    const float* x  = (const float*)d_in[0];
    const float* wh = (const float*)d_in[1];
    const float* bh = (const float*)d_in[2];
    const float* ww = (const float*)d_in[3];
    const float* bw = (const float*)d_in[4];
    float* outp = (float*)d_out;

    const int nbatch = in_sizes[0] / (DIMC * HW * HW);  // = 10
    dim3 grid(nbatch * DIMC);
    dim3 block(512);
    hipLaunchKernelGGL(sep_conv255_mfma, grid, block, 0, stream,
                       x, wh, bh, ww, bw, outp);
}